// Round 5
// baseline (254.393 us; speedup 1.0000x reference)
//
#include <hip/hip_runtime.h>
#include <hip/hip_bf16.h>

typedef float f32x4 __attribute__((ext_vector_type(4)));
typedef short bf16x8 __attribute__((ext_vector_type(8)));
typedef unsigned uint4v __attribute__((ext_vector_type(4)));

#define B_ 32
#define L_ 1024
#define D_ 64
#define J_ 2047   // 2L-1
#define BL_ (B_ * L_)

// packed f32x2 -> bf16x2 (RNE), single instruction
__device__ __forceinline__ unsigned cvt_pk(float lo, float hi) {
    unsigned r;
    asm("v_cvt_pk_bf16_f32 %0, %1, %2" : "=v"(r) : "v"(lo), "v"(hi));
    return r;
}

__device__ __forceinline__ bf16x8 pack8n(const float* p) {
    float4 a = *(const float4*)p;
    float4 c = *(const float4*)(p + 4);
    union { bf16x8 s; uint4v u; } r;
    r.u[0] = cvt_pk(a.x, a.y);
    r.u[1] = cvt_pk(a.z, a.w);
    r.u[2] = cvt_pk(c.x, c.y);
    r.u[3] = cvt_pk(c.z, c.w);
    return r.s;
}

// Detect attn_mask storage: 0 = 1-byte bool, 1 = int32 0/1, 2 = float32 0.0/1.0
__global__ void detect_mask_kernel(const unsigned int* __restrict__ mw, int* __restrict__ flag) {
    if (threadIdx.x == 0) {
        int all01 = 1, allf = 1;
        for (int i = 0; i < 64; ++i) {
            unsigned w = mw[i];
            if (w > 1u) all01 = 0;
            if (w != 0u && w != 0x3F800000u) allf = 0;
        }
        *flag = all01 ? 1 : (allf ? 2 : 0);
    }
}

// Transpose V[b][1024][64] f32 -> vt[b][64][1024] bf16 (global, L2-resident later).
__global__ __launch_bounds__(256) void vtrans(
    const float* __restrict__ V, unsigned short* __restrict__ vt)
{
    __shared__ float tile[64 * 68];
    const int b = blockIdx.x >> 4, mt = blockIdx.x & 15;
    const int m0 = mt * 64;
    const int tid = threadIdx.x;
    {
        const int ml = tid >> 2, dq = tid & 3;
        const float* src = V + (size_t)(b * L_ + m0 + ml) * D_ + dq * 16;
        #pragma unroll
        for (int i = 0; i < 4; ++i)
            *(float4*)&tile[ml * 68 + dq * 16 + i * 4] = *(const float4*)(src + i * 4);
    }
    __syncthreads();
    {
        const int d = tid >> 2, mq = tid & 3;
        unsigned u[8];
        #pragma unroll
        for (int j = 0; j < 8; ++j)
            u[j] = cvt_pk(tile[(mq * 16 + 2 * j) * 68 + d],
                          tile[(mq * 16 + 2 * j + 1) * 68 + d]);
        unsigned short* dst = vt + ((size_t)b * D_ + d) * L_ + m0 + mq * 16;
        *(uint4v*)dst       = *(uint4v*)&u[0];
        *(uint4v*)(dst + 8) = *(uint4v*)&u[4];
    }
}

// Fused: logits (QK^T + stripe(Qp P^T))/8 + mask -> fp32 LDS; online row stats;
// softmax probs written ONCE to attn (nontemporal); PV MFMA vs global bf16 V^T.
// Block = 32 rows x 1024 cols, 8 waves (2 row-tiles x 4 col-splits), 512 thr.
template<int VTG>
__global__ __launch_bounds__(512) void fused_attn(
    const float* __restrict__ Q, const float* __restrict__ K,
    const float* __restrict__ QP, const float* __restrict__ P,
    const void* __restrict__ mask, const int* __restrict__ flagp,
    const unsigned short* __restrict__ vtg, const float* __restrict__ V,
    float* __restrict__ attn, float* __restrict__ out)
{
    __shared__ float slog[32 * 1024];      // 128 KB: fp32 logits, XOR-swizzled 16B slots
    __shared__ float pm[4][32][2];         // per-col-split partial (max, sumexp)

    const int flag = *flagp;
    const int bid = blockIdx.x;
    const int xcd = bid & 7, ii = bid >> 3;
    const int b   = xcd * 4 + (ii >> 5);   // pin each batch's K/P/Vt to one XCD's L2
    const int rb  = ii & 31;
    const int t0b = rb * 32;
    const int tid = threadIdx.x;
    const int lane = tid & 63;
    const int w    = tid >> 6;
    const int wr = w >> 2, wc = w & 3;
    const int t0 = t0b + wr * 16;
    const int lr = lane & 15, lg = lane >> 4;

    bf16x8 aq[2], aqp[2];
    {
        const float* qrow  = Q  + (size_t)((b * L_ + t0 + lr) * D_ + lg * 8);
        const float* qprow = QP + (size_t)((b * L_ + t0 + lr) * D_ + lg * 8);
        aq[0]  = pack8n(qrow);   aq[1]  = pack8n(qrow + 32);
        aqp[0] = pack8n(qprow);  aqp[1] = pack8n(qprow + 32);
    }
    const unsigned char* m8  = (const unsigned char*)mask;
    const int*   m32p = (const int*)mask;
    const float* mfp  = (const float*)mask;

    float m_run[4] = {-1e30f, -1e30f, -1e30f, -1e30f};
    float l_run[4] = {0.f, 0.f, 0.f, 0.f};

    // ---------------- pass 1: logits -> LDS, online stats ----------------
    #pragma unroll 1
    for (int c = 0; c < 4; ++c) {
        const int m0 = wc * 256 + c * 64;
        f32x4 qk[4];
        #pragma unroll
        for (int ct = 0; ct < 4; ++ct) {
            const float* krow = K + (size_t)((b * L_ + m0 + ct * 16 + lr) * D_ + lg * 8);
            f32x4 acc = {0.f, 0.f, 0.f, 0.f};
            acc = __builtin_amdgcn_mfma_f32_16x16x32_bf16(aq[0], pack8n(krow),      acc, 0, 0, 0);
            acc = __builtin_amdgcn_mfma_f32_16x16x32_bf16(aq[1], pack8n(krow + 32), acc, 0, 0, 0);
            qk[ct] = acc;
        }
        const int jb = 1023 + m0 - t0 - 15;
        f32x4 pa[5];
        #pragma unroll
        for (int ss = 0; ss < 5; ++ss) {
            int j = jb + ss * 16 + lr;
            j = j < 0 ? 0 : (j > J_ - 1 ? J_ - 1 : j);   // clamp unused extremes
            const float* prow = P + (size_t)((b * J_ + j) * D_ + lg * 8);
            f32x4 acc = {0.f, 0.f, 0.f, 0.f};
            acc = __builtin_amdgcn_mfma_f32_16x16x32_bf16(aqp[0], pack8n(prow),      acc, 0, 0, 0);
            acc = __builtin_amdgcn_mfma_f32_16x16x32_bf16(aqp[1], pack8n(prow + 32), acc, 0, 0, 0);
            pa[ss] = acc;
        }
        #pragma unroll
        for (int r = 0; r < 4; ++r) {
            const int ti = lg * 4 + r;
            const int t  = t0 + ti;
            const int rl = wr * 16 + ti;
            const int jj = 15 + lr - ti;                 // 0..30
            const int srcl = (lane & 48) | (jj & 15);
            float sv[4];
            #pragma unroll
            for (int ct = 0; ct < 4; ++ct) {
                float v0 = __shfl(pa[ct][r],     srcl);
                float v1 = __shfl(pa[ct + 1][r], srcl);
                float pos = (jj < 16) ? v0 : v1;
                float s = (qk[ct][r] + pos) * 0.125f;
                const int col = m0 + ct * 16 + lr;
                const size_t idx = (size_t)(b * L_ + t) * L_ + col;
                int msk;
                if (flag == 0)      msk = __builtin_nontemporal_load(m8 + idx);
                else if (flag == 1) msk = m32p[idx];
                else                msk = (mfp[idx] != 0.f);
                if (msk) s = -__builtin_inff();
                sv[ct] = s;
                slog[rl * 1024 + (((col >> 2) ^ (rl & 7)) << 2) + (col & 3)] = s;
            }
            float cm = fmaxf(fmaxf(sv[0], sv[1]), fmaxf(sv[2], sv[3]));
            float mn = fmaxf(m_run[r], cm);
            float e = __expf(sv[0] - mn) + __expf(sv[1] - mn)
                    + __expf(sv[2] - mn) + __expf(sv[3] - mn);
            l_run[r] = l_run[r] * __expf(m_run[r] - mn) + e;
            m_run[r] = mn;
        }
    }
    // cross-lane merge within lr group, publish partial stats
    #pragma unroll
    for (int r = 0; r < 4; ++r) {
        float m = m_run[r], l = l_run[r];
        #pragma unroll
        for (int d = 1; d < 16; d <<= 1) {
            float mo = __shfl_xor(m, d);
            float lo = __shfl_xor(l, d);
            float mn = fmaxf(m, mo);
            l = l * __expf(m - mn) + lo * __expf(mo - mn);
            m = mn;
        }
        if (lr == 0) {
            pm[wc][wr * 16 + lg * 4 + r][0] = m;
            pm[wc][wr * 16 + lg * 4 + r][1] = l;
        }
    }
    __syncthreads();

    // ---------------- pass 2: probs (write once) + PV MFMA ----------------
    const int rl = wr * 16 + lr;
    const int t  = t0b + rl;
    float M = fmaxf(fmaxf(pm[0][rl][0], pm[1][rl][0]),
                    fmaxf(pm[2][rl][0], pm[3][rl][0]));
    float Ls = pm[0][rl][1] * __expf(pm[0][rl][0] - M)
             + pm[1][rl][1] * __expf(pm[1][rl][0] - M)
             + pm[2][rl][1] * __expf(pm[2][rl][0] - M)
             + pm[3][rl][1] * __expf(pm[3][rl][0] - M);
    float inv = 1.0f / Ls;
    float* arow = attn + (size_t)(b * L_ + t) * L_;

    f32x4 acc[4] = {{0,0,0,0},{0,0,0,0},{0,0,0,0},{0,0,0,0}};
    #pragma unroll 2
    for (int kc = 0; kc < 8; ++kc) {
        const int colb = wc * 256 + kc * 32 + lg * 8;
        const int s0 = colb >> 2;
        f32x4 x0 = *(f32x4*)&slog[rl * 1024 + ((s0 ^ (rl & 7)) << 2)];
        f32x4 x1 = *(f32x4*)&slog[rl * 1024 + (((s0 + 1) ^ (rl & 7)) << 2)];
        float p0 = __expf(x0[0] - M) * inv, p1 = __expf(x0[1] - M) * inv;
        float p2 = __expf(x0[2] - M) * inv, p3 = __expf(x0[3] - M) * inv;
        float p4 = __expf(x1[0] - M) * inv, p5 = __expf(x1[1] - M) * inv;
        float p6 = __expf(x1[2] - M) * inv, p7 = __expf(x1[3] - M) * inv;
        f32x4 y0 = {p0, p1, p2, p3};
        f32x4 y1 = {p4, p5, p6, p7};
        __builtin_nontemporal_store(y0, (f32x4*)(arow + colb));
        __builtin_nontemporal_store(y1, (f32x4*)(arow + colb + 4));
        union { bf16x8 s; uint4v u; } ap;
        ap.u[0] = cvt_pk(p0, p1); ap.u[1] = cvt_pk(p2, p3);
        ap.u[2] = cvt_pk(p4, p5); ap.u[3] = cvt_pk(p6, p7);
        #pragma unroll
        for (int ct = 0; ct < 4; ++ct) {
            bf16x8 bv;
            if (VTG) {
                bv = *(const bf16x8*)&vtg[((size_t)b * D_ + ct * 16 + lr) * L_ + colb];
            } else {
                const float* vp = V + (size_t)(b * L_ + colb) * D_ + ct * 16 + lr;
                union { bf16x8 s; uint4v u; } bb;
                bb.u[0] = cvt_pk(vp[0],   vp[64]);
                bb.u[1] = cvt_pk(vp[128], vp[192]);
                bb.u[2] = cvt_pk(vp[256], vp[320]);
                bb.u[3] = cvt_pk(vp[384], vp[448]);
                bv = bb.s;
            }
            acc[ct] = __builtin_amdgcn_mfma_f32_16x16x32_bf16(ap.s, bv, acc[ct], 0, 0, 0);
        }
    }
    __syncthreads();                        // all slog reads complete
    // partial O into (now free) slog region: opart[wc][32][64]
    float* opart = slog;
    #pragma unroll
    for (int ct = 0; ct < 4; ++ct) {
        #pragma unroll
        for (int r = 0; r < 4; ++r)
            opart[(wc * 32 + wr * 16 + lg * 4 + r) * 64 + ct * 16 + lr] = acc[ct][r];
    }
    __syncthreads();
    {
        const int row = tid >> 4, dg = (tid & 15) << 2;
        f32x4 o = *(f32x4*)&opart[row * 64 + dg];
        #pragma unroll
        for (int wq = 1; wq < 4; ++wq) {
            f32x4 z = *(f32x4*)&opart[(wq * 32 + row) * 64 + dg];
            o[0] += z[0]; o[1] += z[1]; o[2] += z[2]; o[3] += z[3];
        }
        __builtin_nontemporal_store(o, (f32x4*)(out + (size_t)(b * L_ + t0b + row) * D_ + dg));
    }
}

extern "C" void kernel_launch(void* const* d_in, const int* in_sizes, int n_in,
                              void* d_out, int out_size, void* d_ws, size_t ws_size,
                              hipStream_t stream) {
    const float* q    = (const float*)d_in[0];
    const float* k    = (const float*)d_in[1];
    const float* v    = (const float*)d_in[2];
    const void*  mask = d_in[3];
    const float* P    = (const float*)d_in[4];
    const float* qp   = (const float*)d_in[5];

    float* out  = (float*)d_out;                  // [B, L, D]
    float* attn = out + B_ * L_ * D_;             // [B, L, L]

    int* flag = (int*)d_ws;
    unsigned short* vtg = (unsigned short*)((char*)d_ws + 64);
    const size_t need_vt = 64 + (size_t)B_ * D_ * L_ * 2;

    detect_mask_kernel<<<1, 64, 0, stream>>>((const unsigned int*)mask, flag);
    if (ws_size >= need_vt) {
        vtrans<<<B_ * 16, 256, 0, stream>>>(v, vtg);
        fused_attn<1><<<B_ * 32, 512, 0, stream>>>(q, k, qp, P, mask, flag, vtg, v, attn, out);
    } else {
        fused_attn<0><<<B_ * 32, 512, 0, stream>>>(q, k, qp, P, mask, flag, vtg, v, attn, out);
    }
}

// Round 6
// 235.984 us; speedup vs baseline: 1.0780x; 1.0780x over previous
//
#include <hip/hip_runtime.h>
#include <hip/hip_bf16.h>

typedef float f32x4 __attribute__((ext_vector_type(4)));
typedef short bf16x8 __attribute__((ext_vector_type(8)));
typedef unsigned uint4v __attribute__((ext_vector_type(4)));

#define B_ 32
#define L_ 1024
#define D_ 64
#define J_ 2047   // 2L-1
#define BL_ (B_ * L_)

// packed f32x2 -> bf16x2 (RNE), single instruction
__device__ __forceinline__ unsigned cvt_pk(float lo, float hi) {
    unsigned r;
    asm("v_cvt_pk_bf16_f32 %0, %1, %2" : "=v"(r) : "v"(lo), "v"(hi));
    return r;
}

__device__ __forceinline__ bf16x8 pack8n(const float* p) {
    float4 a = *(const float4*)p;
    float4 c = *(const float4*)(p + 4);
    union { bf16x8 s; uint4v u; } r;
    r.u[0] = cvt_pk(a.x, a.y);
    r.u[1] = cvt_pk(a.z, a.w);
    r.u[2] = cvt_pk(c.x, c.y);
    r.u[3] = cvt_pk(c.z, c.w);
    return r.s;
}

// Detect attn_mask storage: 0 = 1-byte bool, 1 = int32 0/1, 2 = float32 0.0/1.0
__global__ void detect_mask_kernel(const unsigned int* __restrict__ mw, int* __restrict__ flag) {
    if (threadIdx.x == 0) {
        int all01 = 1, allf = 1;
        for (int i = 0; i < 64; ++i) {
            unsigned w = mw[i];
            if (w > 1u) all01 = 0;
            if (w != 0u && w != 0x3F800000u) allf = 0;
        }
        *flag = all01 ? 1 : (allf ? 2 : 0);
    }
}

// Transpose V[b][1024][64] f32 -> vt[b][64][1024] bf16 (global, L2-resident later).
__global__ __launch_bounds__(256) void vtrans(
    const float* __restrict__ V, unsigned short* __restrict__ vt)
{
    __shared__ float tile[64 * 68];
    const int b = blockIdx.x >> 4, mt = blockIdx.x & 15;
    const int m0 = mt * 64;
    const int tid = threadIdx.x;
    {
        const int ml = tid >> 2, dq = tid & 3;
        const float* src = V + (size_t)(b * L_ + m0 + ml) * D_ + dq * 16;
        #pragma unroll
        for (int i = 0; i < 4; ++i)
            *(float4*)&tile[ml * 68 + dq * 16 + i * 4] = *(const float4*)(src + i * 4);
    }
    __syncthreads();
    {
        const int d = tid >> 2, mq = tid & 3;
        unsigned u[8];
        #pragma unroll
        for (int j = 0; j < 8; ++j)
            u[j] = cvt_pk(tile[(mq * 16 + 2 * j) * 68 + d],
                          tile[(mq * 16 + 2 * j + 1) * 68 + d]);
        unsigned short* dst = vt + ((size_t)b * D_ + d) * L_ + m0 + mq * 16;
        *(uint4v*)dst       = *(uint4v*)&u[0];
        *(uint4v*)(dst + 8) = *(uint4v*)&u[4];
    }
}

// Fused: logits (QK^T + stripe(Qp P^T))/8 + mask -> fp32 LDS; online row stats;
// softmax probs written ONCE (nontemporal); PV MFMA vs global bf16 V^T.
// Block = 32 rows x 1024 cols, 16 waves (2 row-tiles x 8 col-splits), 1024 thr.
template<int VTG>
__global__ __launch_bounds__(1024, 4) void fused_attn(
    const float* __restrict__ Q, const float* __restrict__ K,
    const float* __restrict__ QP, const float* __restrict__ P,
    const void* __restrict__ mask, const int* __restrict__ flagp,
    const unsigned short* __restrict__ vtg, const float* __restrict__ V,
    float* __restrict__ attn, float* __restrict__ out)
{
    __shared__ float slog[32 * 1024];      // 128 KB: fp32 logits, XOR-swizzled 16B slots
    __shared__ float pm[8][32][2];         // per-col-split partial (max, sumexp)

    const int flag = *flagp;
    const int bid = blockIdx.x;
    const int xcd = bid & 7, ii = bid >> 3;
    const int b   = xcd * 4 + (ii >> 5);   // pin each batch's K/P/Vt to one XCD's L2
    const int rb  = ii & 31;
    const int t0b = rb * 32;
    const int tid = threadIdx.x;
    const int lane = tid & 63;
    const int w    = tid >> 6;             // 0..15
    const int wr = w >> 3, wc = w & 7;     // 2 row-tiles x 8 col-splits
    const int t0 = t0b + wr * 16;
    const int lr = lane & 15, lg = lane >> 4;

    bf16x8 aq[2], aqp[2];
    {
        const float* qrow  = Q  + (size_t)((b * L_ + t0 + lr) * D_ + lg * 8);
        const float* qprow = QP + (size_t)((b * L_ + t0 + lr) * D_ + lg * 8);
        aq[0]  = pack8n(qrow);   aq[1]  = pack8n(qrow + 32);
        aqp[0] = pack8n(qprow);  aqp[1] = pack8n(qprow + 32);
    }
    const unsigned char* m8  = (const unsigned char*)mask;
    const int*   m32p = (const int*)mask;
    const float* mfp  = (const float*)mask;

    float m_run[4] = {-1e30f, -1e30f, -1e30f, -1e30f};
    float l_run[4] = {0.f, 0.f, 0.f, 0.f};

    // ---------------- pass 1: logits -> LDS, online stats ----------------
    #pragma unroll 1
    for (int c = 0; c < 2; ++c) {
        const int m0 = wc * 128 + c * 64;
        f32x4 qk[4];
        #pragma unroll
        for (int ct = 0; ct < 4; ++ct) {
            const float* krow = K + (size_t)((b * L_ + m0 + ct * 16 + lr) * D_ + lg * 8);
            f32x4 acc = {0.f, 0.f, 0.f, 0.f};
            acc = __builtin_amdgcn_mfma_f32_16x16x32_bf16(aq[0], pack8n(krow),      acc, 0, 0, 0);
            acc = __builtin_amdgcn_mfma_f32_16x16x32_bf16(aq[1], pack8n(krow + 32), acc, 0, 0, 0);
            qk[ct] = acc;
        }
        const int jb = 1023 + m0 - t0 - 15;
        f32x4 pa[5];
        #pragma unroll
        for (int ss = 0; ss < 5; ++ss) {
            int j = jb + ss * 16 + lr;
            j = j < 0 ? 0 : (j > J_ - 1 ? J_ - 1 : j);   // clamp unused extremes
            const float* prow = P + (size_t)((b * J_ + j) * D_ + lg * 8);
            f32x4 acc = {0.f, 0.f, 0.f, 0.f};
            acc = __builtin_amdgcn_mfma_f32_16x16x32_bf16(aqp[0], pack8n(prow),      acc, 0, 0, 0);
            acc = __builtin_amdgcn_mfma_f32_16x16x32_bf16(aqp[1], pack8n(prow + 32), acc, 0, 0, 0);
            pa[ss] = acc;
        }
        #pragma unroll
        for (int r = 0; r < 4; ++r) {
            const int ti = lg * 4 + r;
            const int t  = t0 + ti;
            const int rl = wr * 16 + ti;
            // coalesced mask: one dword (4 bytes = 4 cols) per lane, shfl-redistribute
            const size_t rowoff = (size_t)(b * L_ + t) * L_ + m0;
            unsigned mw;
            if (flag == 0) {
                mw = __builtin_nontemporal_load((const unsigned*)(m8 + rowoff) + lr);
            } else if (flag == 1) {
                int4 mi = ((const int4*)(m32p + rowoff))[lr];
                mw = (mi.x ? 1u : 0u) | (mi.y ? 0x100u : 0u)
                   | (mi.z ? 0x10000u : 0u) | (mi.w ? 0x1000000u : 0u);
            } else {
                float4 mv = ((const float4*)(mfp + rowoff))[lr];
                mw = (mv.x != 0.f ? 1u : 0u) | (mv.y != 0.f ? 0x100u : 0u)
                   | (mv.z != 0.f ? 0x10000u : 0u) | (mv.w != 0.f ? 0x1000000u : 0u);
            }
            const int jj = 15 + lr - ti;                 // 0..30
            const int srcl = (lane & 48) | (jj & 15);
            float sv[4];
            #pragma unroll
            for (int ct = 0; ct < 4; ++ct) {
                float v0 = __shfl(pa[ct][r],     srcl);
                float v1 = __shfl(pa[ct + 1][r], srcl);
                float pos = (jj < 16) ? v0 : v1;
                float s = (qk[ct][r] + pos) * 0.125f;
                unsigned mb = ((unsigned)__shfl((int)mw, (lane & 48) | (ct * 4 + (lr >> 2)))
                               >> ((lr & 3) * 8)) & 0xFFu;
                if (mb) s = -__builtin_inff();
                sv[ct] = s;
                const int col = m0 + ct * 16 + lr;
                slog[rl * 1024 + (((col >> 2) ^ (rl & 7)) << 2) + (col & 3)] = s;
            }
            float cm = fmaxf(fmaxf(sv[0], sv[1]), fmaxf(sv[2], sv[3]));
            float mn = fmaxf(m_run[r], cm);
            float e = __expf(sv[0] - mn) + __expf(sv[1] - mn)
                    + __expf(sv[2] - mn) + __expf(sv[3] - mn);
            l_run[r] = l_run[r] * __expf(m_run[r] - mn) + e;
            m_run[r] = mn;
        }
    }
    // cross-lane merge within lr group, publish partial stats
    #pragma unroll
    for (int r = 0; r < 4; ++r) {
        float m = m_run[r], l = l_run[r];
        #pragma unroll
        for (int d = 1; d < 16; d <<= 1) {
            float mo = __shfl_xor(m, d);
            float lo = __shfl_xor(l, d);
            float mn = fmaxf(m, mo);
            l = l * __expf(m - mn) + lo * __expf(mo - mn);
            m = mn;
        }
        if (lr == 0) {
            pm[wc][wr * 16 + lg * 4 + r][0] = m;
            pm[wc][wr * 16 + lg * 4 + r][1] = l;
        }
    }
    __syncthreads();

    // ---------------- pass 2: probs (write once) + PV MFMA ----------------
    const int rl = wr * 16 + lr;
    const int t  = t0b + rl;
    float M = -1e30f;
    #pragma unroll
    for (int s2 = 0; s2 < 8; ++s2) M = fmaxf(M, pm[s2][rl][0]);
    float Ls = 0.f;
    #pragma unroll
    for (int s2 = 0; s2 < 8; ++s2) Ls += pm[s2][rl][1] * __expf(pm[s2][rl][0] - M);
    float inv = 1.0f / Ls;
    float* arow = attn + (size_t)(b * L_ + t) * L_;

    f32x4 acc[4] = {{0,0,0,0},{0,0,0,0},{0,0,0,0},{0,0,0,0}};
    #pragma unroll
    for (int kc = 0; kc < 4; ++kc) {
        const int colb = wc * 128 + kc * 32 + lg * 8;
        const int s0 = colb >> 2;
        f32x4 x0 = *(f32x4*)&slog[rl * 1024 + ((s0 ^ (rl & 7)) << 2)];
        f32x4 x1 = *(f32x4*)&slog[rl * 1024 + (((s0 + 1) ^ (rl & 7)) << 2)];
        float p0 = __expf(x0[0] - M) * inv, p1 = __expf(x0[1] - M) * inv;
        float p2 = __expf(x0[2] - M) * inv, p3 = __expf(x0[3] - M) * inv;
        float p4 = __expf(x1[0] - M) * inv, p5 = __expf(x1[1] - M) * inv;
        float p6 = __expf(x1[2] - M) * inv, p7 = __expf(x1[3] - M) * inv;
        f32x4 y0 = {p0, p1, p2, p3};
        f32x4 y1 = {p4, p5, p6, p7};
        __builtin_nontemporal_store(y0, (f32x4*)(arow + colb));
        __builtin_nontemporal_store(y1, (f32x4*)(arow + colb + 4));
        union { bf16x8 s; uint4v u; } ap;
        ap.u[0] = cvt_pk(p0, p1); ap.u[1] = cvt_pk(p2, p3);
        ap.u[2] = cvt_pk(p4, p5); ap.u[3] = cvt_pk(p6, p7);
        #pragma unroll
        for (int ct = 0; ct < 4; ++ct) {
            bf16x8 bv;
            if (VTG) {
                bv = *(const bf16x8*)&vtg[((size_t)b * D_ + ct * 16 + lr) * L_ + colb];
            } else {
                const float* vp = V + (size_t)(b * L_ + colb) * D_ + ct * 16 + lr;
                union { bf16x8 s; uint4v u; } bb;
                bb.u[0] = cvt_pk(vp[0],   vp[64]);
                bb.u[1] = cvt_pk(vp[128], vp[192]);
                bb.u[2] = cvt_pk(vp[256], vp[320]);
                bb.u[3] = cvt_pk(vp[384], vp[448]);
                bv = bb.s;
            }
            acc[ct] = __builtin_amdgcn_mfma_f32_16x16x32_bf16(ap.s, bv, acc[ct], 0, 0, 0);
        }
    }
    __syncthreads();                        // all slog reads complete
    // partial O into (now free) slog region: opart[wc][32][68-padded]
    float* opart = slog;
    #pragma unroll
    for (int ct = 0; ct < 4; ++ct) {
        #pragma unroll
        for (int r = 0; r < 4; ++r)
            opart[(wc * 32 + wr * 16 + lg * 4 + r) * 68 + ct * 16 + lr] = acc[ct][r];
    }
    __syncthreads();
    if (tid < 512) {
        const int row = tid >> 4, dg = (tid & 15) << 2;
        f32x4 o = *(f32x4*)&opart[row * 68 + dg];
        #pragma unroll
        for (int wq = 1; wq < 8; ++wq) {
            f32x4 z = *(f32x4*)&opart[(wq * 32 + row) * 68 + dg];
            o[0] += z[0]; o[1] += z[1]; o[2] += z[2]; o[3] += z[3];
        }
        __builtin_nontemporal_store(o, (f32x4*)(out + (size_t)(b * L_ + t0b + row) * D_ + dg));
    }
}

extern "C" void kernel_launch(void* const* d_in, const int* in_sizes, int n_in,
                              void* d_out, int out_size, void* d_ws, size_t ws_size,
                              hipStream_t stream) {
    const float* q    = (const float*)d_in[0];
    const float* k    = (const float*)d_in[1];
    const float* v    = (const float*)d_in[2];
    const void*  mask = d_in[3];
    const float* P    = (const float*)d_in[4];
    const float* qp   = (const float*)d_in[5];

    float* out  = (float*)d_out;                  // [B, L, D]
    float* attn = out + B_ * L_ * D_;             // [B, L, L]

    int* flag = (int*)d_ws;
    unsigned short* vtg = (unsigned short*)((char*)d_ws + 64);
    const size_t need_vt = 64 + (size_t)B_ * D_ * L_ * 2;

    detect_mask_kernel<<<1, 64, 0, stream>>>((const unsigned int*)mask, flag);
    if (ws_size >= need_vt) {
        vtrans<<<B_ * 16, 256, 0, stream>>>(v, vtg);
        fused_attn<1><<<B_ * 32, 1024, 0, stream>>>(q, k, qp, P, mask, flag, vtg, v, attn, out);
    } else {
        fused_attn<0><<<B_ * 32, 1024, 0, stream>>>(q, k, qp, P, mask, flag, vtg, v, attn, out);
    }
}